// Round 1
// baseline (1357.603 us; speedup 1.0000x reference)
//
#include <hip/hip_runtime.h>

#define N_NODES 100000
#define N_EDGES 640000
#define IN_DIM  128
#define OUT_DIM 128
#define N_REL   16
#define EPB     64   // edges per block in edge kernel (E % EPB == 0)

// ---------------- counting sort of edges by relation ----------------

__global__ void k_zero(int* __restrict__ counts) {
    if (threadIdx.x < N_REL) counts[threadIdx.x] = 0;
}

__global__ void k_hist(const int* __restrict__ etype, int* __restrict__ counts) {
    __shared__ int bins[N_REL];
    int t = threadIdx.x;
    if (t < N_REL) bins[t] = 0;
    __syncthreads();
    int e = blockIdx.x * blockDim.x + t;
    if (e < N_EDGES) atomicAdd(&bins[etype[e]], 1);
    __syncthreads();
    if (t < N_REL && bins[t]) atomicAdd(&counts[t], bins[t]);
}

__global__ void k_scan(const int* __restrict__ counts, int* __restrict__ cursor) {
    if (threadIdx.x == 0) {
        int s = 0;
        for (int r = 0; r < N_REL; ++r) { cursor[r] = s; s += counts[r]; }
    }
}

__global__ void k_scatter(const int* __restrict__ etype, int* __restrict__ cursor,
                          int* __restrict__ sorted) {
    __shared__ int bins[N_REL];
    __shared__ int base[N_REL];
    int t = threadIdx.x;
    if (t < N_REL) bins[t] = 0;
    __syncthreads();
    int e = blockIdx.x * blockDim.x + t;
    int rel = 0;
    bool valid = (e < N_EDGES);
    if (valid) { rel = etype[e]; atomicAdd(&bins[rel], 1); }
    __syncthreads();
    if (t < N_REL) {
        base[t] = bins[t] ? atomicAdd(&cursor[t], bins[t]) : 0;
        bins[t] = 0;
    }
    __syncthreads();
    if (valid) {
        int p = atomicAdd(&bins[rel], 1);
        sorted[base[rel] + p] = e;
    }
}

// ---------------- self-loop transform: out = x @ SW + bias ----------------
// block = 128 threads (one per output col), 8 nodes per block.
__global__ __launch_bounds__(128) void k_self(const float* __restrict__ x,
                                              const float* __restrict__ sw,
                                              const float* __restrict__ bias,
                                              float* __restrict__ out) {
    __shared__ float s_x[8][IN_DIM];
    int t = threadIdx.x;
    int n0 = blockIdx.x * 8;
    for (int i = t; i < 8 * IN_DIM; i += 128) {
        int r = i >> 7, j = i & 127;
        s_x[r][j] = x[(size_t)(n0 + r) * IN_DIM + j];
    }
    __syncthreads();
    float acc[8] = {0.f,0.f,0.f,0.f,0.f,0.f,0.f,0.f};
    for (int k = 0; k < IN_DIM; ++k) {
        float w = sw[k * OUT_DIM + t];   // coalesced, L1/L2-resident
        #pragma unroll
        for (int i = 0; i < 8; ++i) acc[i] += s_x[i][k] * w;  // LDS broadcast
    }
    float b = bias[t];
    #pragma unroll
    for (int i = 0; i < 8; ++i)
        out[(size_t)(n0 + i) * OUT_DIM + t] = acc[i] + b;
}

// ---------------- edge messages: out[dst] += x[src] @ W[rel] ----------------
// block = 256 threads, EPB=64 sorted edges. Thread tile: 4 cols x 8 edges.
__global__ __launch_bounds__(256) void k_edge(const float* __restrict__ x,
                                              const float* __restrict__ rw,
                                              const int* __restrict__ src,
                                              const int* __restrict__ dst,
                                              const int* __restrict__ etype,
                                              const int* __restrict__ sorted,
                                              float* __restrict__ out) {
    __shared__ int s_src[EPB], s_dst[EPB], s_rel[EPB];
    __shared__ float s_x[EPB][IN_DIM];   // 32 KB
    int t = threadIdx.x;
    int e0 = blockIdx.x * EPB;

    if (t < EPB) {
        int eid = sorted[e0 + t];
        s_src[t] = src[eid];
        s_dst[t] = dst[eid];
        s_rel[t] = etype[eid];
    }
    __syncthreads();

    // gather x rows of the 64 source nodes (coalesced 128-wide per row)
    for (int i = t; i < EPB * IN_DIM; i += 256) {
        int e = i >> 7, j = i & 127;
        s_x[e][j] = x[(size_t)s_src[e] * IN_DIM + j];
    }
    // relation-uniform check (broadcast LDS reads, block-uniform result)
    int rel0 = s_rel[0];
    bool uni = true;
    for (int i = 1; i < EPB; ++i) uni &= (s_rel[i] == rel0);
    __syncthreads();

    int cg = t & 31;   // col group: cols [4*cg, 4*cg+4)
    int eg = t >> 5;   // edge group: edges [8*eg, 8*eg+8)

    if (uni) {
        const float4* Wr = (const float4*)(rw + (size_t)rel0 * IN_DIM * OUT_DIM);
        float acc[8][4];
        #pragma unroll
        for (int i = 0; i < 8; ++i) { acc[i][0]=0.f; acc[i][1]=0.f; acc[i][2]=0.f; acc[i][3]=0.f; }
        for (int k = 0; k < IN_DIM; ++k) {
            float4 w = Wr[k * 32 + cg];          // full 512B row coalesced per wave
            #pragma unroll
            for (int i = 0; i < 8; ++i) {
                float xv = s_x[eg * 8 + i][k];   // 2 addrs/bank per wave -> free
                acc[i][0] += xv * w.x; acc[i][1] += xv * w.y;
                acc[i][2] += xv * w.z; acc[i][3] += xv * w.w;
            }
        }
        #pragma unroll
        for (int i = 0; i < 8; ++i) {
            int e = eg * 8 + i;
            float* o = out + (size_t)s_dst[e] * OUT_DIM + cg * 4;
            atomicAdd(o + 0, acc[i][0]);
            atomicAdd(o + 1, acc[i][1]);
            atomicAdd(o + 2, acc[i][2]);
            atomicAdd(o + 3, acc[i][3]);
        }
    } else {
        // rare: relation-boundary block (<=15 of 10000). per-edge relation.
        for (int i = 0; i < 8; ++i) {
            int e = eg * 8 + i;
            int rel = s_rel[e];
            const float4* Wr = (const float4*)(rw + (size_t)rel * IN_DIM * OUT_DIM);
            float a0=0.f, a1=0.f, a2=0.f, a3=0.f;
            for (int k = 0; k < IN_DIM; ++k) {
                float4 w = Wr[k * 32 + cg];
                float xv = s_x[e][k];
                a0 += xv * w.x; a1 += xv * w.y; a2 += xv * w.z; a3 += xv * w.w;
            }
            float* o = out + (size_t)s_dst[e] * OUT_DIM + cg * 4;
            atomicAdd(o + 0, a0); atomicAdd(o + 1, a1);
            atomicAdd(o + 2, a2); atomicAdd(o + 3, a3);
        }
    }
}

// ---------------- relu epilogue ----------------
__global__ void k_relu(float* __restrict__ out) {
    int i = blockIdx.x * blockDim.x + threadIdx.x;
    float4* o4 = (float4*)out;
    const int n4 = N_NODES * OUT_DIM / 4;
    if (i < n4) {
        float4 v = o4[i];
        v.x = fmaxf(v.x, 0.f); v.y = fmaxf(v.y, 0.f);
        v.z = fmaxf(v.z, 0.f); v.w = fmaxf(v.w, 0.f);
        o4[i] = v;
    }
}

extern "C" void kernel_launch(void* const* d_in, const int* in_sizes, int n_in,
                              void* d_out, int out_size, void* d_ws, size_t ws_size,
                              hipStream_t stream) {
    const float* x     = (const float*)d_in[0];
    const int*   eidx  = (const int*)d_in[1];   // (2, E): [0:E]=src, [E:2E]=dst
    const int*   etype = (const int*)d_in[2];
    const float* rw    = (const float*)d_in[3]; // (16, 128, 128)
    const float* sw    = (const float*)d_in[4]; // (128, 128)
    const float* bias  = (const float*)d_in[5]; // (128,)
    float* out = (float*)d_out;

    int* counts = (int*)d_ws;          // 16
    int* cursor = counts + N_REL;      // 16
    int* sorted = cursor + N_REL;      // E
    const int* src = eidx;
    const int* dst = eidx + N_EDGES;

    k_zero<<<1, 64, 0, stream>>>(counts);
    k_hist<<<(N_EDGES + 255) / 256, 256, 0, stream>>>(etype, counts);
    k_scan<<<1, 64, 0, stream>>>(counts, cursor);
    k_scatter<<<(N_EDGES + 255) / 256, 256, 0, stream>>>(etype, cursor, sorted);

    k_self<<<N_NODES / 8, 128, 0, stream>>>(x, sw, bias, out);
    k_edge<<<N_EDGES / EPB, 256, 0, stream>>>(x, rw, src, dst, etype, sorted, out);
    k_relu<<<(N_NODES * OUT_DIM / 4 + 255) / 256, 256, 0, stream>>>(out);
}

// Round 2
// 673.924 us; speedup vs baseline: 2.0145x; 2.0145x over previous
//
#include <hip/hip_runtime.h>

#define N_NODES 100000
#define N_EDGES 640000
#define IN_DIM  128
#define OUT_DIM 128
#define N_REL   16
#define EPB     64                       // edges per block in phase-1
#define NB_SCAN ((N_NODES + 255) / 256)  // 391 scan blocks

typedef unsigned short u16;
typedef unsigned int   u32;

__device__ inline u16 f2bf(float f) {               // round-to-nearest-even
    u32 u = __builtin_bit_cast(u32, f);
    return (u16)((u + 0x7fffu + ((u >> 16) & 1u)) >> 16);
}
__device__ inline float bf2f(u16 s) {
    u32 u = ((u32)s) << 16;
    return __builtin_bit_cast(float, u);
}

// ---------------- histograms: relation bins + dst-node counts ----------------
__global__ __launch_bounds__(256) void k_hist(const int* __restrict__ etype,
                                              const int* __restrict__ dst,
                                              int* __restrict__ counts_rel,
                                              int* __restrict__ dst_count) {
    __shared__ int bins[N_REL];
    int t = threadIdx.x;
    if (t < N_REL) bins[t] = 0;
    __syncthreads();
    int e = blockIdx.x * 256 + t;
    if (e < N_EDGES) {
        atomicAdd(&bins[etype[e]], 1);
        atomicAdd(&dst_count[dst[e]], 1);   // 640k atomics over 100k addrs: low contention
    }
    __syncthreads();
    if (t < N_REL && bins[t]) atomicAdd(&counts_rel[t], bins[t]);
}

__global__ void k_scan_rel(const int* __restrict__ counts, int* __restrict__ cursor) {
    if (threadIdx.x == 0) {
        int s = 0;
        for (int r = 0; r < N_REL; ++r) { cursor[r] = s; s += counts[r]; }
    }
}

// relation counting-sort: sorted[slot] = edge id, slots grouped by relation
__global__ __launch_bounds__(256) void k_scatter_rel(const int* __restrict__ etype,
                                                     int* __restrict__ cursor,
                                                     int* __restrict__ sorted) {
    __shared__ int bins[N_REL];
    __shared__ int base[N_REL];
    int t = threadIdx.x;
    if (t < N_REL) bins[t] = 0;
    __syncthreads();
    int e = blockIdx.x * 256 + t;
    int rel = 0;
    bool valid = (e < N_EDGES);
    if (valid) { rel = etype[e]; atomicAdd(&bins[rel], 1); }
    __syncthreads();
    if (t < N_REL) {
        base[t] = bins[t] ? atomicAdd(&cursor[t], bins[t]) : 0;
        bins[t] = 0;
    }
    __syncthreads();
    if (valid) {
        int p = atomicAdd(&bins[rel], 1);
        sorted[base[rel] + p] = e;
    }
}

// ---------------- exclusive scan over dst_count -> row_ptr (3 kernels) ------
__global__ __launch_bounds__(256) void k_scan1(const int* __restrict__ dst_count,
                                               int* __restrict__ row_ptr,
                                               int* __restrict__ part) {
    __shared__ int buf[2][256];
    int t = threadIdx.x;
    int i = blockIdx.x * 256 + t;
    int v = (i < N_NODES) ? dst_count[i] : 0;
    buf[0][t] = v;
    __syncthreads();
    int cur = 0;
    #pragma unroll
    for (int off = 1; off < 256; off <<= 1) {
        int nxt = cur ^ 1;
        int s = buf[cur][t];
        if (t >= off) s += buf[cur][t - off];
        buf[nxt][t] = s;
        __syncthreads();
        cur = nxt;
    }
    int inc = buf[cur][t];
    if (i < N_NODES) row_ptr[i] = inc - v;       // block-local exclusive
    if (t == 255) part[blockIdx.x] = inc;        // block total
}

__global__ __launch_bounds__(512) void k_scan2(int* __restrict__ part) {
    __shared__ int buf[2][512];
    int t = threadIdx.x;
    int v = (t < NB_SCAN) ? part[t] : 0;
    buf[0][t] = v;
    __syncthreads();
    int cur = 0;
    #pragma unroll
    for (int off = 1; off < 512; off <<= 1) {
        int nxt = cur ^ 1;
        int s = buf[cur][t];
        if (t >= off) s += buf[cur][t - off];
        buf[nxt][t] = s;
        __syncthreads();
        cur = nxt;
    }
    int inc = buf[cur][t];
    if (t < NB_SCAN) part[t] = inc - v;          // exclusive block offsets
}

__global__ __launch_bounds__(256) void k_scan3(int* __restrict__ row_ptr,
                                               const int* __restrict__ part,
                                               int* __restrict__ cursor_dst) {
    int t = threadIdx.x;
    int i = blockIdx.x * 256 + t;
    if (i < N_NODES) {
        int r = row_ptr[i] + part[blockIdx.x];
        row_ptr[i] = r;
        cursor_dst[i] = r;
    }
    if (i == 0) row_ptr[N_NODES] = N_EDGES;
}

// csr[pos] = slot index (into msgs), grouped per dst node
__global__ __launch_bounds__(256) void k_csr(const int* __restrict__ sorted,
                                             const int* __restrict__ dst,
                                             int* __restrict__ cursor_dst,
                                             int* __restrict__ csr) {
    int s = blockIdx.x * 256 + threadIdx.x;
    if (s < N_EDGES) {
        int e = sorted[s];
        int p = atomicAdd(&cursor_dst[dst[e]], 1);
        csr[p] = s;
    }
}

// ---------------- self-loop transform: out = x @ SW + bias ------------------
__global__ __launch_bounds__(128) void k_self(const float* __restrict__ x,
                                              const float* __restrict__ sw,
                                              const float* __restrict__ bias,
                                              float* __restrict__ out) {
    __shared__ float s_x[8][IN_DIM];
    int t = threadIdx.x;
    int n0 = blockIdx.x * 8;
    for (int i = t; i < 8 * IN_DIM; i += 128) {
        int r = i >> 7, j = i & 127;
        s_x[r][j] = x[(size_t)(n0 + r) * IN_DIM + j];
    }
    __syncthreads();
    float acc[8] = {0.f,0.f,0.f,0.f,0.f,0.f,0.f,0.f};
    for (int k = 0; k < IN_DIM; ++k) {
        float w = sw[k * OUT_DIM + t];
        #pragma unroll
        for (int i = 0; i < 8; ++i) acc[i] += s_x[i][k] * w;
    }
    float b = bias[t];
    #pragma unroll
    for (int i = 0; i < 8; ++i)
        out[(size_t)(n0 + i) * OUT_DIM + t] = acc[i] + b;
}

// ---------------- phase 1: per-edge messages -> msgs[slot] (bf16) -----------
// block = 256 threads, 64 rel-sorted edges. Thread tile: 4 cols x 8 edges.
__global__ __launch_bounds__(256) void k_msg(const float* __restrict__ x,
                                             const float* __restrict__ rw,
                                             const int* __restrict__ src,
                                             const int* __restrict__ etype,
                                             const int* __restrict__ sorted,
                                             u16* __restrict__ msgs) {
    __shared__ int s_src[EPB], s_rel[EPB];
    __shared__ float s_x[EPB][IN_DIM];   // 32 KB
    int t = threadIdx.x;
    int e0 = blockIdx.x * EPB;

    if (t < EPB) {
        int eid = sorted[e0 + t];
        s_src[t] = src[eid];
        s_rel[t] = etype[eid];
    }
    __syncthreads();

    for (int i = t; i < EPB * IN_DIM; i += 256) {
        int e = i >> 7, j = i & 127;
        s_x[e][j] = x[(size_t)s_src[e] * IN_DIM + j];
    }
    int rel0 = s_rel[0];
    bool uni = true;
    for (int i = 1; i < EPB; ++i) uni &= (s_rel[i] == rel0);
    __syncthreads();

    int cg = t & 31;   // cols [4*cg, 4*cg+4)
    int eg = t >> 5;   // edges [8*eg, 8*eg+8)
    ushort4* m4 = (ushort4*)msgs;

    if (uni) {
        const float4* Wr = (const float4*)(rw + (size_t)rel0 * IN_DIM * OUT_DIM);
        float acc[8][4];
        #pragma unroll
        for (int i = 0; i < 8; ++i) { acc[i][0]=0.f; acc[i][1]=0.f; acc[i][2]=0.f; acc[i][3]=0.f; }
        for (int k = 0; k < IN_DIM; ++k) {
            float4 w = Wr[k * 32 + cg];
            #pragma unroll
            for (int i = 0; i < 8; ++i) {
                float xv = s_x[eg * 8 + i][k];
                acc[i][0] += xv * w.x; acc[i][1] += xv * w.y;
                acc[i][2] += xv * w.z; acc[i][3] += xv * w.w;
            }
        }
        #pragma unroll
        for (int i = 0; i < 8; ++i) {
            int slot = e0 + eg * 8 + i;
            ushort4 p;
            p.x = f2bf(acc[i][0]); p.y = f2bf(acc[i][1]);
            p.z = f2bf(acc[i][2]); p.w = f2bf(acc[i][3]);
            m4[(size_t)slot * 32 + cg] = p;   // contiguous 16 KB per block
        }
    } else {
        for (int i = 0; i < 8; ++i) {
            int e = eg * 8 + i;
            const float4* Wr = (const float4*)(rw + (size_t)s_rel[e] * IN_DIM * OUT_DIM);
            float a0=0.f, a1=0.f, a2=0.f, a3=0.f;
            for (int k = 0; k < IN_DIM; ++k) {
                float4 w = Wr[k * 32 + cg];
                float xv = s_x[e][k];
                a0 += xv * w.x; a1 += xv * w.y; a2 += xv * w.z; a3 += xv * w.w;
            }
            ushort4 p; p.x = f2bf(a0); p.y = f2bf(a1); p.z = f2bf(a2); p.w = f2bf(a3);
            m4[(size_t)(e0 + e) * 32 + cg] = p;
        }
    }
}

// ---------------- phase 2: per-node gather + relu (no atomics) --------------
// one wave per node, 2 cols per lane
__global__ __launch_bounds__(256) void k_gather(const int* __restrict__ row_ptr,
                                                const int* __restrict__ csr,
                                                const u16* __restrict__ msgs,
                                                float* __restrict__ out) {
    int wid  = (blockIdx.x * 256 + threadIdx.x) >> 6;
    int lane = threadIdx.x & 63;
    if (wid >= N_NODES) return;
    int r0 = row_ptr[wid], r1 = row_ptr[wid + 1];
    float a0 = 0.f, a1 = 0.f;
    const u32* m2 = (const u32*)msgs;            // 2 bf16 per u32
    for (int i = r0; i < r1; ++i) {
        int slot = csr[i];
        u32 v = m2[(size_t)slot * 64 + lane];    // coalesced 256B per wave
        a0 += bf2f((u16)(v & 0xffffu));
        a1 += bf2f((u16)(v >> 16));
    }
    float2* o2 = (float2*)out;
    size_t oi = (size_t)wid * 64 + lane;
    float2 v = o2[oi];
    v.x = fmaxf(v.x + a0, 0.f);
    v.y = fmaxf(v.y + a1, 0.f);
    o2[oi] = v;
}

// ---------------- fallback (round-1 atomic path, small ws) ------------------
__global__ __launch_bounds__(256) void k_edge_atomic(const float* __restrict__ x,
                                              const float* __restrict__ rw,
                                              const int* __restrict__ src,
                                              const int* __restrict__ dst,
                                              const int* __restrict__ etype,
                                              const int* __restrict__ sorted,
                                              float* __restrict__ out) {
    __shared__ int s_src[EPB], s_dst[EPB], s_rel[EPB];
    __shared__ float s_x[EPB][IN_DIM];
    int t = threadIdx.x;
    int e0 = blockIdx.x * EPB;
    if (t < EPB) {
        int eid = sorted[e0 + t];
        s_src[t] = src[eid]; s_dst[t] = dst[eid]; s_rel[t] = etype[eid];
    }
    __syncthreads();
    for (int i = t; i < EPB * IN_DIM; i += 256) {
        int e = i >> 7, j = i & 127;
        s_x[e][j] = x[(size_t)s_src[e] * IN_DIM + j];
    }
    int rel0 = s_rel[0];
    bool uni = true;
    for (int i = 1; i < EPB; ++i) uni &= (s_rel[i] == rel0);
    __syncthreads();
    int cg = t & 31, eg = t >> 5;
    for (int i = 0; i < 8; ++i) {
        int e = eg * 8 + i;
        int rel = uni ? rel0 : s_rel[e];
        const float4* Wr = (const float4*)(rw + (size_t)rel * IN_DIM * OUT_DIM);
        float a0=0.f, a1=0.f, a2=0.f, a3=0.f;
        for (int k = 0; k < IN_DIM; ++k) {
            float4 w = Wr[k * 32 + cg];
            float xv = s_x[e][k];
            a0 += xv * w.x; a1 += xv * w.y; a2 += xv * w.z; a3 += xv * w.w;
        }
        float* o = out + (size_t)s_dst[e] * OUT_DIM + cg * 4;
        atomicAdd(o + 0, a0); atomicAdd(o + 1, a1);
        atomicAdd(o + 2, a2); atomicAdd(o + 3, a3);
    }
}

__global__ void k_relu(float* __restrict__ out) {
    int i = blockIdx.x * blockDim.x + threadIdx.x;
    float4* o4 = (float4*)out;
    const int n4 = N_NODES * OUT_DIM / 4;
    if (i < n4) {
        float4 v = o4[i];
        v.x = fmaxf(v.x, 0.f); v.y = fmaxf(v.y, 0.f);
        v.z = fmaxf(v.z, 0.f); v.w = fmaxf(v.w, 0.f);
        o4[i] = v;
    }
}

extern "C" void kernel_launch(void* const* d_in, const int* in_sizes, int n_in,
                              void* d_out, int out_size, void* d_ws, size_t ws_size,
                              hipStream_t stream) {
    const float* x     = (const float*)d_in[0];
    const int*   eidx  = (const int*)d_in[1];   // (2, E): [0:E]=src, [E:2E]=dst
    const int*   etype = (const int*)d_in[2];
    const float* rw    = (const float*)d_in[3];
    const float* sw    = (const float*)d_in[4];
    const float* bias  = (const float*)d_in[5];
    float* out = (float*)d_out;
    const int* src = eidx;
    const int* dst = eidx + N_EDGES;

    // ---- workspace layout ----
    int* counts_rel = (int*)d_ws;                  // 16
    int* cursor_rel = counts_rel + 16;             // 16
    int* part       = cursor_rel + 16;             // 512
    int* dst_count  = part + 512;                  // N
    int* row_ptr    = dst_count + N_NODES;         // N+1
    int* cursor_dst = row_ptr + N_NODES + 1;       // N
    int* sorted     = cursor_dst + N_NODES;        // E
    int* csr        = sorted + N_EDGES;            // E
    size_t msgs_off = ((size_t)((char*)(csr + N_EDGES) - (char*)d_ws) + 255) & ~(size_t)255;
    u16* msgs       = (u16*)((char*)d_ws + msgs_off);
    size_t need     = msgs_off + (size_t)N_EDGES * 128 * sizeof(u16);

    const int EB = (N_EDGES + 255) / 256;   // 2500

    if (ws_size >= need) {
        // zero counts_rel..dst_count in one shot (covers 16+16+512+N ints)
        hipMemsetAsync(d_ws, 0, (size_t)(544 + N_NODES) * sizeof(int), stream);
        k_hist<<<EB, 256, 0, stream>>>(etype, dst, counts_rel, dst_count);
        k_scan_rel<<<1, 64, 0, stream>>>(counts_rel, cursor_rel);
        k_scatter_rel<<<EB, 256, 0, stream>>>(etype, cursor_rel, sorted);
        k_scan1<<<NB_SCAN, 256, 0, stream>>>(dst_count, row_ptr, part);
        k_scan2<<<1, 512, 0, stream>>>(part);
        k_scan3<<<NB_SCAN, 256, 0, stream>>>(row_ptr, part, cursor_dst);
        k_csr<<<EB, 256, 0, stream>>>(sorted, dst, cursor_dst, csr);

        k_self<<<N_NODES / 8, 128, 0, stream>>>(x, sw, bias, out);
        k_msg<<<N_EDGES / EPB, 256, 0, stream>>>(x, rw, src, etype, sorted, msgs);
        k_gather<<<(N_NODES * 64 + 255) / 256, 256, 0, stream>>>(row_ptr, csr, msgs, out);
    } else {
        // fallback: round-1 atomic path (needs only rel-sort scratch)
        hipMemsetAsync(d_ws, 0, 32 * sizeof(int), stream);
        k_hist<<<EB, 256, 0, stream>>>(etype, dst, counts_rel, counts_rel /*dummy reuse*/);
        k_scan_rel<<<1, 64, 0, stream>>>(counts_rel, cursor_rel);
        k_scatter_rel<<<EB, 256, 0, stream>>>(etype, cursor_rel, sorted);
        k_self<<<N_NODES / 8, 128, 0, stream>>>(x, sw, bias, out);
        k_edge_atomic<<<N_EDGES / EPB, 256, 0, stream>>>(x, rw, src, dst, etype, sorted, out);
        k_relu<<<(N_NODES * OUT_DIM / 4 + 255) / 256, 256, 0, stream>>>(out);
    }
}

// Round 3
// 529.648 us; speedup vs baseline: 2.5632x; 1.2724x over previous
//
#include <hip/hip_runtime.h>

#define N_NODES 100000
#define N_EDGES 640000
#define IN_DIM  128
#define OUT_DIM 128
#define N_REL   16
#define EPB     64
#define NB_SCAN ((N_NODES + 255) / 256)

typedef unsigned short u16;
typedef unsigned int   u32;
typedef __attribute__((ext_vector_type(8))) short bf16x8;
typedef __attribute__((ext_vector_type(4))) float f32x4;

__device__ inline u16 f2bf(float f) {               // round-to-nearest-even
    u32 u = __builtin_bit_cast(u32, f);
    return (u16)((u + 0x7fffu + ((u >> 16) & 1u)) >> 16);
}
__device__ inline float bf2f(u16 s) {
    u32 u = ((u32)s) << 16;
    return __builtin_bit_cast(float, u);
}

// ---------------- dtype conversions ----------------
// x (fp32) -> xb (bf16), 4 elems/thread, exact grid
__global__ __launch_bounds__(256) void k_cvt_x(const float* __restrict__ x,
                                               u16* __restrict__ xb) {
    int i = blockIdx.x * 256 + threadIdx.x;
    float4 v = ((const float4*)x)[i];
    ushort4 p; p.x = f2bf(v.x); p.y = f2bf(v.y); p.z = f2bf(v.z); p.w = f2bf(v.w);
    ((ushort4*)xb)[i] = p;
}

// W[r][k][n] (+ self as r=16) -> Wt[r][n][k] bf16 (k contiguous for frag loads)
__global__ __launch_bounds__(256) void k_cvt_w(const float* __restrict__ rw,
                                               const float* __restrict__ sw,
                                               u16* __restrict__ wt) {
    int i = blockIdx.x * 256 + threadIdx.x;     // over 17*16384, exact
    int r = i >> 14, rem = i & 16383, k = rem >> 7, n = rem & 127;
    float v = (r < 16) ? rw[i] : sw[rem];
    wt[(size_t)r * 16384 + n * 128 + k] = f2bf(v);
}

// ---------------- histograms ----------------
__global__ __launch_bounds__(256) void k_hist(const int* __restrict__ etype,
                                              const int* __restrict__ dst,
                                              int* __restrict__ counts_rel,
                                              int* __restrict__ dst_count) {
    __shared__ int bins[N_REL];
    int t = threadIdx.x;
    if (t < N_REL) bins[t] = 0;
    __syncthreads();
    int e = blockIdx.x * 256 + t;
    if (e < N_EDGES) {
        atomicAdd(&bins[etype[e]], 1);
        atomicAdd(&dst_count[dst[e]], 1);
    }
    __syncthreads();
    if (t < N_REL && bins[t]) atomicAdd(&counts_rel[t], bins[t]);
}

__global__ __launch_bounds__(256) void k_hist_rel(const int* __restrict__ etype,
                                                  int* __restrict__ counts_rel) {
    __shared__ int bins[N_REL];
    int t = threadIdx.x;
    if (t < N_REL) bins[t] = 0;
    __syncthreads();
    int e = blockIdx.x * 256 + t;
    if (e < N_EDGES) atomicAdd(&bins[etype[e]], 1);
    __syncthreads();
    if (t < N_REL && bins[t]) atomicAdd(&counts_rel[t], bins[t]);
}

__global__ void k_scan_rel(const int* __restrict__ counts, int* __restrict__ cursor) {
    if (threadIdx.x == 0) {
        int s = 0;
        for (int r = 0; r < N_REL; ++r) { cursor[r] = s; s += counts[r]; }
    }
}

__global__ __launch_bounds__(256) void k_scatter_rel(const int* __restrict__ etype,
                                                     int* __restrict__ cursor,
                                                     int* __restrict__ sorted) {
    __shared__ int bins[N_REL];
    __shared__ int base[N_REL];
    int t = threadIdx.x;
    if (t < N_REL) bins[t] = 0;
    __syncthreads();
    int e = blockIdx.x * 256 + t;
    int rel = 0;
    bool valid = (e < N_EDGES);
    if (valid) { rel = etype[e]; atomicAdd(&bins[rel], 1); }
    __syncthreads();
    if (t < N_REL) {
        base[t] = bins[t] ? atomicAdd(&cursor[t], bins[t]) : 0;
        bins[t] = 0;
    }
    __syncthreads();
    if (valid) {
        int p = atomicAdd(&bins[rel], 1);
        sorted[base[rel] + p] = e;
    }
}

// ---------------- exclusive scan over dst_count -> row_ptr ----------------
__global__ __launch_bounds__(256) void k_scan1(const int* __restrict__ dst_count,
                                               int* __restrict__ row_ptr,
                                               int* __restrict__ part) {
    __shared__ int buf[2][256];
    int t = threadIdx.x;
    int i = blockIdx.x * 256 + t;
    int v = (i < N_NODES) ? dst_count[i] : 0;
    buf[0][t] = v;
    __syncthreads();
    int cur = 0;
    #pragma unroll
    for (int off = 1; off < 256; off <<= 1) {
        int nxt = cur ^ 1;
        int s = buf[cur][t];
        if (t >= off) s += buf[cur][t - off];
        buf[nxt][t] = s;
        __syncthreads();
        cur = nxt;
    }
    int inc = buf[cur][t];
    if (i < N_NODES) row_ptr[i] = inc - v;
    if (t == 255) part[blockIdx.x] = inc;
}

__global__ __launch_bounds__(512) void k_scan2(int* __restrict__ part) {
    __shared__ int buf[2][512];
    int t = threadIdx.x;
    int v = (t < NB_SCAN) ? part[t] : 0;
    buf[0][t] = v;
    __syncthreads();
    int cur = 0;
    #pragma unroll
    for (int off = 1; off < 512; off <<= 1) {
        int nxt = cur ^ 1;
        int s = buf[cur][t];
        if (t >= off) s += buf[cur][t - off];
        buf[nxt][t] = s;
        __syncthreads();
        cur = nxt;
    }
    int inc = buf[cur][t];
    if (t < NB_SCAN) part[t] = inc - v;
}

__global__ __launch_bounds__(256) void k_scan3(int* __restrict__ row_ptr,
                                               const int* __restrict__ part,
                                               int* __restrict__ cursor_dst) {
    int t = threadIdx.x;
    int i = blockIdx.x * 256 + t;
    if (i < N_NODES) {
        int r = row_ptr[i] + part[blockIdx.x];
        row_ptr[i] = r;
        cursor_dst[i] = r;
    }
    if (i == 0) row_ptr[N_NODES] = N_EDGES;
}

// pos[slot] = this edge's position in dst-grouped order
__global__ __launch_bounds__(256) void k_pos(const int* __restrict__ sorted,
                                             const int* __restrict__ dst,
                                             int* __restrict__ cursor_dst,
                                             int* __restrict__ pos) {
    int s = blockIdx.x * 256 + threadIdx.x;
    if (s < N_EDGES) {
        int e = sorted[s];
        pos[s] = atomicAdd(&cursor_dst[dst[e]], 1);
    }
}

// ---------------- self transform (MFMA): out = xb @ SW + bias ----------------
__global__ __launch_bounds__(256) void k_self_mfma(const u16* __restrict__ xb,
                                                   const u16* __restrict__ wt,
                                                   const float* __restrict__ bias,
                                                   float* __restrict__ out) {
    __shared__ u16 s_x[64][136];    // +8 pad: 2-way LDS aliasing only
    __shared__ u16 s_w[128][136];
    int t = threadIdx.x;
    int n0 = blockIdx.x * 64;
    for (int i = t; i < 64 * 16; i += 256) {
        int row = i >> 4, ch = i & 15;
        int node = n0 + row; if (node >= N_NODES) node = N_NODES - 1;
        *(uint4*)&s_x[row][ch * 8] = ((const uint4*)(xb + (size_t)node * 128))[ch];
    }
    const u16* wsrc = wt + (size_t)16 * 16384;   // self weight = "relation 16"
    for (int i = t; i < 128 * 16; i += 256) {
        int row = i >> 4, ch = i & 15;
        *(uint4*)&s_w[row][ch * 8] = ((const uint4*)(wsrc + row * 128))[ch];
    }
    __syncthreads();
    int lane = t & 63, w = t >> 6;
    int n = lane & 15, q = lane >> 4;
    int node = n0 + w * 16 + n;
    bf16x8 bx[4];
    #pragma unroll
    for (int kk = 0; kk < 4; ++kk)
        bx[kk] = *(const bf16x8*)&s_x[w * 16 + n][kk * 32 + q * 8];
    #pragma unroll
    for (int c = 0; c < 8; ++c) {
        f32x4 acc = {0.f, 0.f, 0.f, 0.f};
        #pragma unroll
        for (int kk = 0; kk < 4; ++kk) {
            bf16x8 aw = *(const bf16x8*)&s_w[c * 16 + n][kk * 32 + q * 8];
            acc = __builtin_amdgcn_mfma_f32_16x16x32_bf16(aw, bx[kk], acc, 0, 0, 0);
        }
        if (node < N_NODES) {
            float4 b4 = *(const float4*)&bias[c * 16 + q * 4];
            float4 o;
            o.x = acc[0] + b4.x; o.y = acc[1] + b4.y;
            o.z = acc[2] + b4.z; o.w = acc[3] + b4.w;
            *(float4*)&out[(size_t)node * 128 + c * 16 + q * 4] = o;
        }
    }
}

// ---------------- phase 1 (MFMA): dst-grouped bf16 messages ----------------
// D = A(W^T tile 16x32) * B(x rows 16x32): lane(n,q) holds msg[edge n][c*16+q*4+r]
__global__ __launch_bounds__(256) void k_msg_mfma(const u16* __restrict__ xb,
                                                  const u16* __restrict__ wt,
                                                  const int* __restrict__ src,
                                                  const int* __restrict__ etype,
                                                  const int* __restrict__ sorted,
                                                  const int* __restrict__ pos,
                                                  u16* __restrict__ msgs) {
    __shared__ int s_src[EPB], s_rel[EPB], s_pos[EPB];
    __shared__ u16 s_x[64][136];
    __shared__ u16 s_w[128][136];
    int t = threadIdx.x;
    int e0 = blockIdx.x * EPB;
    if (t < EPB) {
        int eid = sorted[e0 + t];
        s_src[t] = src[eid];
        s_rel[t] = etype[eid];
        s_pos[t] = pos[e0 + t];
    }
    __syncthreads();
    for (int i = t; i < 64 * 16; i += 256) {
        int row = i >> 4, ch = i & 15;
        *(uint4*)&s_x[row][ch * 8] = ((const uint4*)(xb + (size_t)s_src[row] * 128))[ch];
    }
    int rel0 = s_rel[0];
    bool uni = true;
    for (int i = 1; i < EPB; ++i) uni &= (s_rel[i] == rel0);
    const u16* wsrc = wt + (size_t)rel0 * 16384;
    for (int i = t; i < 128 * 16; i += 256) {
        int row = i >> 4, ch = i & 15;
        *(uint4*)&s_w[row][ch * 8] = ((const uint4*)(wsrc + row * 128))[ch];
    }
    __syncthreads();

    if (uni) {
        int lane = t & 63, w = t >> 6;
        int n = lane & 15, q = lane >> 4;
        int p = s_pos[w * 16 + n];
        bf16x8 bx[4];
        #pragma unroll
        for (int kk = 0; kk < 4; ++kk)
            bx[kk] = *(const bf16x8*)&s_x[w * 16 + n][kk * 32 + q * 8];
        #pragma unroll
        for (int c = 0; c < 8; ++c) {
            f32x4 acc = {0.f, 0.f, 0.f, 0.f};
            #pragma unroll
            for (int kk = 0; kk < 4; ++kk) {
                bf16x8 aw = *(const bf16x8*)&s_w[c * 16 + n][kk * 32 + q * 8];
                acc = __builtin_amdgcn_mfma_f32_16x16x32_bf16(aw, bx[kk], acc, 0, 0, 0);
            }
            ushort4 pk;
            pk.x = f2bf(acc[0]); pk.y = f2bf(acc[1]);
            pk.z = f2bf(acc[2]); pk.w = f2bf(acc[3]);
            *(ushort4*)&msgs[(size_t)p * 128 + c * 16 + q * 4] = pk;
        }
    } else {
        // rare relation-boundary block (<=15 of 10000): scalar path
        int cg = t & 31, eg = t >> 5;
        for (int i = 0; i < 8; ++i) {
            int e = eg * 8 + i;
            const u16* Wr = wt + (size_t)s_rel[e] * 16384;   // [n][k] layout
            float a[4] = {0.f, 0.f, 0.f, 0.f};
            for (int k2 = 0; k2 < 128; ++k2) {
                float xv = bf2f(s_x[e][k2]);
                #pragma unroll
                for (int j = 0; j < 4; ++j)
                    a[j] += xv * bf2f(Wr[(cg * 4 + j) * 128 + k2]);
            }
            int p = s_pos[e];
            ushort4 pk;
            pk.x = f2bf(a[0]); pk.y = f2bf(a[1]); pk.z = f2bf(a[2]); pk.w = f2bf(a[3]);
            *(ushort4*)&msgs[(size_t)p * 128 + cg * 4] = pk;
        }
    }
}

// ---------------- phase 2: sequential per-node gather + relu ----------------
__global__ __launch_bounds__(256) void k_gather(const int* __restrict__ row_ptr,
                                                const u16* __restrict__ msgs,
                                                float* __restrict__ out) {
    int wid  = (blockIdx.x * 256 + threadIdx.x) >> 6;
    int lane = threadIdx.x & 63;
    if (wid >= N_NODES) return;
    int r0 = row_ptr[wid], r1 = row_ptr[wid + 1];
    float a0 = 0.f, a1 = 0.f;
    const u32* m2 = (const u32*)msgs;
    for (int i = r0; i < r1; ++i) {
        u32 v = m2[(size_t)i * 64 + lane];   // contiguous rows: streaming read
        a0 += bf2f((u16)(v & 0xffffu));
        a1 += bf2f((u16)(v >> 16));
    }
    float2* o2 = (float2*)out;
    size_t oi = (size_t)wid * 64 + lane;
    float2 v = o2[oi];
    v.x = fmaxf(v.x + a0, 0.f);
    v.y = fmaxf(v.y + a1, 0.f);
    o2[oi] = v;
}

// ---------------- fallback (atomic path, small ws) ----------------
__global__ __launch_bounds__(128) void k_self_old(const float* __restrict__ x,
                                                  const float* __restrict__ sw,
                                                  const float* __restrict__ bias,
                                                  float* __restrict__ out) {
    __shared__ float s_x[8][IN_DIM];
    int t = threadIdx.x;
    int n0 = blockIdx.x * 8;
    for (int i = t; i < 8 * IN_DIM; i += 128) {
        int r = i >> 7, j = i & 127;
        s_x[r][j] = x[(size_t)(n0 + r) * IN_DIM + j];
    }
    __syncthreads();
    float acc[8] = {0.f,0.f,0.f,0.f,0.f,0.f,0.f,0.f};
    for (int k = 0; k < IN_DIM; ++k) {
        float w = sw[k * OUT_DIM + t];
        #pragma unroll
        for (int i = 0; i < 8; ++i) acc[i] += s_x[i][k] * w;
    }
    float b = bias[t];
    #pragma unroll
    for (int i = 0; i < 8; ++i)
        out[(size_t)(n0 + i) * OUT_DIM + t] = acc[i] + b;
}

__global__ __launch_bounds__(256) void k_edge_atomic(const float* __restrict__ x,
                                              const float* __restrict__ rw,
                                              const int* __restrict__ src,
                                              const int* __restrict__ dst,
                                              const int* __restrict__ etype,
                                              const int* __restrict__ sorted,
                                              float* __restrict__ out) {
    __shared__ int s_src[EPB], s_dst[EPB], s_rel[EPB];
    __shared__ float s_x[EPB][IN_DIM];
    int t = threadIdx.x;
    int e0 = blockIdx.x * EPB;
    if (t < EPB) {
        int eid = sorted[e0 + t];
        s_src[t] = src[eid]; s_dst[t] = dst[eid]; s_rel[t] = etype[eid];
    }
    __syncthreads();
    for (int i = t; i < EPB * IN_DIM; i += 256) {
        int e = i >> 7, j = i & 127;
        s_x[e][j] = x[(size_t)s_src[e] * IN_DIM + j];
    }
    int rel0 = s_rel[0];
    bool uni = true;
    for (int i = 1; i < EPB; ++i) uni &= (s_rel[i] == rel0);
    __syncthreads();
    int cg = t & 31, eg = t >> 5;
    for (int i = 0; i < 8; ++i) {
        int e = eg * 8 + i;
        int rel = uni ? rel0 : s_rel[e];
        const float4* Wr = (const float4*)(rw + (size_t)rel * IN_DIM * OUT_DIM);
        float a0=0.f, a1=0.f, a2=0.f, a3=0.f;
        for (int k = 0; k < IN_DIM; ++k) {
            float4 w = Wr[k * 32 + cg];
            float xv = s_x[e][k];
            a0 += xv * w.x; a1 += xv * w.y; a2 += xv * w.z; a3 += xv * w.w;
        }
        float* o = out + (size_t)s_dst[e] * OUT_DIM + cg * 4;
        atomicAdd(o + 0, a0); atomicAdd(o + 1, a1);
        atomicAdd(o + 2, a2); atomicAdd(o + 3, a3);
    }
}

__global__ void k_relu(float* __restrict__ out) {
    int i = blockIdx.x * blockDim.x + threadIdx.x;
    float4* o4 = (float4*)out;
    const int n4 = N_NODES * OUT_DIM / 4;
    if (i < n4) {
        float4 v = o4[i];
        v.x = fmaxf(v.x, 0.f); v.y = fmaxf(v.y, 0.f);
        v.z = fmaxf(v.z, 0.f); v.w = fmaxf(v.w, 0.f);
        o4[i] = v;
    }
}

extern "C" void kernel_launch(void* const* d_in, const int* in_sizes, int n_in,
                              void* d_out, int out_size, void* d_ws, size_t ws_size,
                              hipStream_t stream) {
    const float* x     = (const float*)d_in[0];
    const int*   eidx  = (const int*)d_in[1];
    const int*   etype = (const int*)d_in[2];
    const float* rw    = (const float*)d_in[3];
    const float* sw    = (const float*)d_in[4];
    const float* bias  = (const float*)d_in[5];
    float* out = (float*)d_out;
    const int* src = eidx;
    const int* dst = eidx + N_EDGES;

    // ---- workspace layout ----
    int* counts_rel = (int*)d_ws;                  // 16
    int* cursor_rel = counts_rel + 16;             // 16
    int* part       = cursor_rel + 16;             // 512
    int* dst_count  = part + 512;                  // N
    int* row_ptr    = dst_count + N_NODES;         // N+1
    int* cursor_dst = row_ptr + N_NODES + 1;       // N
    int* sorted     = cursor_dst + N_NODES;        // E
    int* pos        = sorted + N_EDGES;            // E
    size_t off = (((char*)(pos + N_EDGES) - (char*)d_ws) + 255) & ~(size_t)255;
    u16* xb   = (u16*)((char*)d_ws + off);         // N*128 bf16
    u16* wtb  = xb + (size_t)N_NODES * 128;        // 17*16384 bf16 (transposed)
    u16* msgs = wtb + 17 * 16384;                  // E*128 bf16, dst-grouped
    size_t need = (size_t)((char*)(msgs + (size_t)N_EDGES * 128) - (char*)d_ws);

    const int EB = (N_EDGES + 255) / 256;   // 2500

    if (ws_size >= need) {
        hipMemsetAsync(d_ws, 0, (size_t)(544 + N_NODES) * sizeof(int), stream);
        k_cvt_x<<<N_NODES * IN_DIM / 4 / 256, 256, 0, stream>>>(x, xb);
        k_cvt_w<<<17 * 16384 / 256, 256, 0, stream>>>(rw, sw, wtb);
        k_hist<<<EB, 256, 0, stream>>>(etype, dst, counts_rel, dst_count);
        k_scan_rel<<<1, 64, 0, stream>>>(counts_rel, cursor_rel);
        k_scatter_rel<<<EB, 256, 0, stream>>>(etype, cursor_rel, sorted);
        k_scan1<<<NB_SCAN, 256, 0, stream>>>(dst_count, row_ptr, part);
        k_scan2<<<1, 512, 0, stream>>>(part);
        k_scan3<<<NB_SCAN, 256, 0, stream>>>(row_ptr, part, cursor_dst);
        k_pos<<<EB, 256, 0, stream>>>(sorted, dst, cursor_dst, pos);

        k_self_mfma<<<(N_NODES + 63) / 64, 256, 0, stream>>>(xb, wtb, bias, out);
        k_msg_mfma<<<N_EDGES / EPB, 256, 0, stream>>>(xb, wtb, src, etype, sorted, pos, msgs);
        k_gather<<<(N_NODES * 64 + 255) / 256, 256, 0, stream>>>(row_ptr, msgs, out);
    } else {
        // fallback: atomic path (needs only rel-sort scratch)
        hipMemsetAsync(counts_rel, 0, 16 * sizeof(int), stream);
        k_hist_rel<<<EB, 256, 0, stream>>>(etype, counts_rel);
        k_scan_rel<<<1, 64, 0, stream>>>(counts_rel, cursor_rel);
        k_scatter_rel<<<EB, 256, 0, stream>>>(etype, cursor_rel, sorted);
        k_self_old<<<N_NODES / 8, 128, 0, stream>>>(x, sw, bias, out);
        k_edge_atomic<<<N_EDGES / EPB, 256, 0, stream>>>(x, rw, src, dst, etype, sorted, out);
        k_relu<<<(N_NODES * OUT_DIM / 4 + 255) / 256, 256, 0, stream>>>(out);
    }
}

// Round 4
// 404.559 us; speedup vs baseline: 3.3558x; 1.3092x over previous
//
#include <hip/hip_runtime.h>

#define N_NODES 100000
#define N_EDGES 640000
#define IN_DIM  128
#define OUT_DIM 128
#define N_REL   16
#define EPB     64
#define PAD     1024                     // max relation-padding slop (16 rel * 63, rounded up)
#define NB_SCAN ((N_NODES + 255) / 256)

typedef unsigned short u16;
typedef unsigned int   u32;
typedef __attribute__((ext_vector_type(8))) short bf16x8;
typedef __attribute__((ext_vector_type(4))) float f32x4;

__device__ inline u16 f2bf(float f) {               // round-to-nearest-even
    u32 u = __builtin_bit_cast(u32, f);
    return (u16)((u + 0x7fffu + ((u >> 16) & 1u)) >> 16);
}
__device__ inline float bf2f(u16 s) {
    u32 u = ((u32)s) << 16;
    return __builtin_bit_cast(float, u);
}

// ---------------- dtype conversions ----------------
__global__ __launch_bounds__(256) void k_cvt_x(const float* __restrict__ x,
                                               u16* __restrict__ xb) {
    int i = blockIdx.x * 256 + threadIdx.x;
    float4 v = ((const float4*)x)[i];
    ushort4 p; p.x = f2bf(v.x); p.y = f2bf(v.y); p.z = f2bf(v.z); p.w = f2bf(v.w);
    ((ushort4*)xb)[i] = p;
}

// W[r][k][n] (+ self as r=16) -> Wt[r][n][k] bf16
__global__ __launch_bounds__(256) void k_cvt_w(const float* __restrict__ rw,
                                               const float* __restrict__ sw,
                                               u16* __restrict__ wt) {
    int i = blockIdx.x * 256 + threadIdx.x;     // over 17*16384, exact
    int r = i >> 14, rem = i & 16383, k = rem >> 7, n = rem & 127;
    float v = (r < 16) ? rw[i] : sw[rem];
    wt[(size_t)r * 16384 + n * 128 + k] = f2bf(v);
}

// ---------------- histograms ----------------
__global__ __launch_bounds__(256) void k_hist(const int* __restrict__ etype,
                                              const int* __restrict__ dst,
                                              int* __restrict__ counts_rel,
                                              int* __restrict__ dst_count) {
    __shared__ int bins[N_REL];
    int t = threadIdx.x;
    if (t < N_REL) bins[t] = 0;
    __syncthreads();
    int e = blockIdx.x * 256 + t;
    if (e < N_EDGES) {
        atomicAdd(&bins[etype[e]], 1);
        atomicAdd(&dst_count[dst[e]], 1);
    }
    __syncthreads();
    if (t < N_REL && bins[t]) atomicAdd(&counts_rel[t], bins[t]);
}

__global__ __launch_bounds__(256) void k_hist_rel(const int* __restrict__ etype,
                                                  int* __restrict__ counts_rel) {
    __shared__ int bins[N_REL];
    int t = threadIdx.x;
    if (t < N_REL) bins[t] = 0;
    __syncthreads();
    int e = blockIdx.x * 256 + t;
    if (e < N_EDGES) atomicAdd(&bins[etype[e]], 1);
    __syncthreads();
    if (t < N_REL && bins[t]) atomicAdd(&counts_rel[t], bins[t]);
}

// padded (to 64) segment starts; seg[16] = E_pad
__global__ void k_scan_rel_pad(const int* __restrict__ counts, int* __restrict__ cursor,
                               int* __restrict__ seg) {
    if (threadIdx.x == 0) {
        int s = 0;
        for (int r = 0; r < N_REL; ++r) {
            cursor[r] = s; seg[r] = s;
            s += (counts[r] + 63) & ~63;
        }
        seg[N_REL] = s;
    }
}

__global__ void k_scan_rel(const int* __restrict__ counts, int* __restrict__ cursor) {
    if (threadIdx.x == 0) {
        int s = 0;
        for (int r = 0; r < N_REL; ++r) { cursor[r] = s; s += counts[r]; }
    }
}

// fill padding slots with sentinel N_EDGES + r (encodes relation)
__global__ __launch_bounds__(256) void k_fill(const int* __restrict__ counts,
                                              const int* __restrict__ seg,
                                              int* __restrict__ sorted) {
    int t = threadIdx.x;
    for (int r = 0; r < N_REL; ++r) {
        int b = seg[r] + counts[r], e2 = seg[r + 1];
        if (b + t < e2) sorted[b + t] = N_EDGES + r;   // pad < 64 per segment
    }
    for (int i = seg[N_REL] + t; i < N_EDGES + PAD; i += 256)
        sorted[i] = N_EDGES + (N_REL - 1);
}

__global__ __launch_bounds__(256) void k_scatter_rel(const int* __restrict__ etype,
                                                     int* __restrict__ cursor,
                                                     int* __restrict__ sorted) {
    __shared__ int bins[N_REL];
    __shared__ int base[N_REL];
    int t = threadIdx.x;
    if (t < N_REL) bins[t] = 0;
    __syncthreads();
    int e = blockIdx.x * 256 + t;
    int rel = 0;
    bool valid = (e < N_EDGES);
    if (valid) { rel = etype[e]; atomicAdd(&bins[rel], 1); }
    __syncthreads();
    if (t < N_REL) {
        base[t] = bins[t] ? atomicAdd(&cursor[t], bins[t]) : 0;
        bins[t] = 0;
    }
    __syncthreads();
    if (valid) {
        int p = atomicAdd(&bins[rel], 1);
        sorted[base[rel] + p] = e;
    }
}

// ---------------- exclusive scan over dst_count -> row_ptr ----------------
__global__ __launch_bounds__(256) void k_scan1(const int* __restrict__ dst_count,
                                               int* __restrict__ row_ptr,
                                               int* __restrict__ part) {
    __shared__ int buf[2][256];
    int t = threadIdx.x;
    int i = blockIdx.x * 256 + t;
    int v = (i < N_NODES) ? dst_count[i] : 0;
    buf[0][t] = v;
    __syncthreads();
    int cur = 0;
    #pragma unroll
    for (int off = 1; off < 256; off <<= 1) {
        int nxt = cur ^ 1;
        int s = buf[cur][t];
        if (t >= off) s += buf[cur][t - off];
        buf[nxt][t] = s;
        __syncthreads();
        cur = nxt;
    }
    int inc = buf[cur][t];
    if (i < N_NODES) row_ptr[i] = inc - v;
    if (t == 255) part[blockIdx.x] = inc;
}

__global__ __launch_bounds__(512) void k_scan2(int* __restrict__ part) {
    __shared__ int buf[2][512];
    int t = threadIdx.x;
    int v = (t < NB_SCAN) ? part[t] : 0;
    buf[0][t] = v;
    __syncthreads();
    int cur = 0;
    #pragma unroll
    for (int off = 1; off < 512; off <<= 1) {
        int nxt = cur ^ 1;
        int s = buf[cur][t];
        if (t >= off) s += buf[cur][t - off];
        buf[nxt][t] = s;
        __syncthreads();
        cur = nxt;
    }
    int inc = buf[cur][t];
    if (t < NB_SCAN) part[t] = inc - v;
}

__global__ __launch_bounds__(256) void k_scan3(int* __restrict__ row_ptr,
                                               const int* __restrict__ part,
                                               int* __restrict__ cursor_dst) {
    int t = threadIdx.x;
    int i = blockIdx.x * 256 + t;
    if (i < N_NODES) {
        int r = row_ptr[i] + part[blockIdx.x];
        row_ptr[i] = r;
        cursor_dst[i] = r;
    }
    if (i == 0) row_ptr[N_NODES] = N_EDGES;
}

// pos[slot] = this edge's position in dst-grouped order (slots incl. padding)
__global__ __launch_bounds__(256) void k_pos(const int* __restrict__ sorted,
                                             const int* __restrict__ dst,
                                             int* __restrict__ cursor_dst,
                                             int* __restrict__ pos) {
    int s = blockIdx.x * 256 + threadIdx.x;
    if (s < N_EDGES + PAD) {
        int e = sorted[s];
        if (e < N_EDGES) pos[s] = atomicAdd(&cursor_dst[dst[e]], 1);
    }
}

// ---------------- self transform (MFMA, LDS-free) ----------------
// wave handles 64 nodes (4 groups of 16); fragments straight from global.
__global__ __launch_bounds__(256, 4) void k_self_mfma(const u16* __restrict__ xb,
                                                      const u16* __restrict__ wt,
                                                      const float* __restrict__ bias,
                                                      float* __restrict__ out) {
    int t = threadIdx.x;
    int w = t >> 6, lane = t & 63;
    int n = lane & 15, q = lane >> 4;
    int n0 = blockIdx.x * 256 + w * 64;
    const u16* wr = wt + (size_t)16 * 16384;     // self weight = "relation 16"

    bf16x8 bx[4][4];
    int node[4];
    #pragma unroll
    for (int g = 0; g < 4; ++g) {
        node[g] = n0 + g * 16 + n;
        int rn = node[g] < N_NODES ? node[g] : N_NODES - 1;
        const u16* xrow = xb + (size_t)rn * 128 + q * 8;
        #pragma unroll
        for (int kk = 0; kk < 4; ++kk)
            bx[g][kk] = *(const bf16x8*)(xrow + kk * 32);
    }
    #pragma unroll
    for (int c = 0; c < 8; ++c) {
        bf16x8 aw[4];
        const u16* wrow = wr + (c * 16 + n) * 128 + q * 8;
        #pragma unroll
        for (int kk = 0; kk < 4; ++kk)
            aw[kk] = *(const bf16x8*)(wrow + kk * 32);
        float4 b4 = *(const float4*)&bias[c * 16 + q * 4];
        #pragma unroll
        for (int g = 0; g < 4; ++g) {
            f32x4 acc = {0.f, 0.f, 0.f, 0.f};
            #pragma unroll
            for (int kk = 0; kk < 4; ++kk)
                acc = __builtin_amdgcn_mfma_f32_16x16x32_bf16(aw[kk], bx[g][kk], acc, 0, 0, 0);
            if (node[g] < N_NODES) {
                float4 o;
                o.x = acc[0] + b4.x; o.y = acc[1] + b4.y;
                o.z = acc[2] + b4.z; o.w = acc[3] + b4.w;
                *(float4*)&out[(size_t)node[g] * 128 + c * 16 + q * 4] = o;
            }
        }
    }
}

// ---------------- phase 1 (MFMA, LDS-free): dst-grouped bf16 messages ------
// block = 256 edges; wave handles 64 edges (relation-uniform by 64-padding).
__global__ __launch_bounds__(256, 4) void k_msg_mfma(const u16* __restrict__ xb,
                                                     const u16* __restrict__ wt,
                                                     const int* __restrict__ src,
                                                     const int* __restrict__ etype,
                                                     const int* __restrict__ sorted,
                                                     const int* __restrict__ pos,
                                                     u16* __restrict__ msgs) {
    __shared__ int s_src[256], s_pos[256];
    __shared__ int s_relw[4];
    int t = threadIdx.x;
    int e0 = blockIdx.x * 256;
    int eid = sorted[e0 + t];
    if (eid < N_EDGES) {
        s_src[t] = src[eid];
        s_pos[t] = pos[e0 + t];
    } else {
        s_src[t] = 0;
        s_pos[t] = N_EDGES + t;              // dump row (races across blocks OK)
    }
    if ((t & 63) == 0)
        s_relw[t >> 6] = (eid < N_EDGES) ? etype[eid] : (eid - N_EDGES);
    __syncthreads();

    int w = t >> 6, lane = t & 63;
    int n = lane & 15, q = lane >> 4;
    const u16* wr = wt + (size_t)s_relw[w] * 16384;
    int ebase = w * 64;

    bf16x8 bx[4][4];
    int p[4];
    #pragma unroll
    for (int g = 0; g < 4; ++g) {
        int en = ebase + g * 16 + n;
        const u16* xrow = xb + (size_t)s_src[en] * 128 + q * 8;
        p[g] = s_pos[en];
        #pragma unroll
        for (int kk = 0; kk < 4; ++kk)
            bx[g][kk] = *(const bf16x8*)(xrow + kk * 32);
    }
    #pragma unroll
    for (int c = 0; c < 8; ++c) {
        bf16x8 aw[4];
        const u16* wrow = wr + (c * 16 + n) * 128 + q * 8;
        #pragma unroll
        for (int kk = 0; kk < 4; ++kk)
            aw[kk] = *(const bf16x8*)(wrow + kk * 32);
        #pragma unroll
        for (int g = 0; g < 4; ++g) {
            f32x4 acc = {0.f, 0.f, 0.f, 0.f};
            #pragma unroll
            for (int kk = 0; kk < 4; ++kk)
                acc = __builtin_amdgcn_mfma_f32_16x16x32_bf16(aw[kk], bx[g][kk], acc, 0, 0, 0);
            ushort4 pk;
            pk.x = f2bf(acc[0]); pk.y = f2bf(acc[1]);
            pk.z = f2bf(acc[2]); pk.w = f2bf(acc[3]);
            *(ushort4*)&msgs[(size_t)p[g] * 128 + c * 16 + q * 4] = pk;
        }
    }
}

// ---------------- phase 2: sequential per-node gather + relu ----------------
__global__ __launch_bounds__(256) void k_gather(const int* __restrict__ row_ptr,
                                                const u16* __restrict__ msgs,
                                                float* __restrict__ out) {
    int wid  = (blockIdx.x * 256 + threadIdx.x) >> 6;
    int lane = threadIdx.x & 63;
    if (wid >= N_NODES) return;
    int r0 = row_ptr[wid], r1 = row_ptr[wid + 1];
    const u32* m2 = (const u32*)msgs;
    float a0 = 0.f, a1 = 0.f, b0 = 0.f, b1 = 0.f;
    int i = r0;
    for (; i + 1 < r1; i += 2) {
        u32 v0 = m2[(size_t)i * 64 + lane];
        u32 v1 = m2[(size_t)(i + 1) * 64 + lane];
        a0 += bf2f((u16)(v0 & 0xffffu)); a1 += bf2f((u16)(v0 >> 16));
        b0 += bf2f((u16)(v1 & 0xffffu)); b1 += bf2f((u16)(v1 >> 16));
    }
    if (i < r1) {
        u32 v0 = m2[(size_t)i * 64 + lane];
        a0 += bf2f((u16)(v0 & 0xffffu)); a1 += bf2f((u16)(v0 >> 16));
    }
    a0 += b0; a1 += b1;
    float2* o2 = (float2*)out;
    size_t oi = (size_t)wid * 64 + lane;
    float2 v = o2[oi];
    v.x = fmaxf(v.x + a0, 0.f);
    v.y = fmaxf(v.y + a1, 0.f);
    o2[oi] = v;
}

// ---------------- fallback (atomic path, small ws) ----------------
__global__ __launch_bounds__(128) void k_self_old(const float* __restrict__ x,
                                                  const float* __restrict__ sw,
                                                  const float* __restrict__ bias,
                                                  float* __restrict__ out) {
    __shared__ float s_x[8][IN_DIM];
    int t = threadIdx.x;
    int n0 = blockIdx.x * 8;
    for (int i = t; i < 8 * IN_DIM; i += 128) {
        int r = i >> 7, j = i & 127;
        s_x[r][j] = x[(size_t)(n0 + r) * IN_DIM + j];
    }
    __syncthreads();
    float acc[8] = {0.f,0.f,0.f,0.f,0.f,0.f,0.f,0.f};
    for (int k = 0; k < IN_DIM; ++k) {
        float w = sw[k * OUT_DIM + t];
        #pragma unroll
        for (int i = 0; i < 8; ++i) acc[i] += s_x[i][k] * w;
    }
    float b = bias[t];
    #pragma unroll
    for (int i = 0; i < 8; ++i)
        out[(size_t)(n0 + i) * OUT_DIM + t] = acc[i] + b;
}

__global__ __launch_bounds__(256) void k_edge_atomic(const float* __restrict__ x,
                                              const float* __restrict__ rw,
                                              const int* __restrict__ src,
                                              const int* __restrict__ dst,
                                              const int* __restrict__ etype,
                                              const int* __restrict__ sorted,
                                              float* __restrict__ out) {
    __shared__ int s_src[EPB], s_dst[EPB], s_rel[EPB];
    __shared__ float s_x[EPB][IN_DIM];
    int t = threadIdx.x;
    int e0 = blockIdx.x * EPB;
    if (t < EPB) {
        int eid = sorted[e0 + t];
        s_src[t] = src[eid]; s_dst[t] = dst[eid]; s_rel[t] = etype[eid];
    }
    __syncthreads();
    for (int i = t; i < EPB * IN_DIM; i += 256) {
        int e = i >> 7, j = i & 127;
        s_x[e][j] = x[(size_t)s_src[e] * IN_DIM + j];
    }
    int rel0 = s_rel[0];
    bool uni = true;
    for (int i = 1; i < EPB; ++i) uni &= (s_rel[i] == rel0);
    __syncthreads();
    int cg = t & 31, eg = t >> 5;
    for (int i = 0; i < 8; ++i) {
        int e = eg * 8 + i;
        int rel = uni ? rel0 : s_rel[e];
        const float4* Wr = (const float4*)(rw + (size_t)rel * IN_DIM * OUT_DIM);
        float a0=0.f, a1=0.f, a2=0.f, a3=0.f;
        for (int k = 0; k < 128; ++k) {
            float4 w = Wr[k * 32 + cg];
            float xv = s_x[e][k];
            a0 += xv * w.x; a1 += xv * w.y; a2 += xv * w.z; a3 += xv * w.w;
        }
        float* o = out + (size_t)s_dst[e] * OUT_DIM + cg * 4;
        atomicAdd(o + 0, a0); atomicAdd(o + 1, a1);
        atomicAdd(o + 2, a2); atomicAdd(o + 3, a3);
    }
}

__global__ void k_relu(float* __restrict__ out) {
    int i = blockIdx.x * blockDim.x + threadIdx.x;
    float4* o4 = (float4*)out;
    const int n4 = N_NODES * OUT_DIM / 4;
    if (i < n4) {
        float4 v = o4[i];
        v.x = fmaxf(v.x, 0.f); v.y = fmaxf(v.y, 0.f);
        v.z = fmaxf(v.z, 0.f); v.w = fmaxf(v.w, 0.f);
        o4[i] = v;
    }
}

extern "C" void kernel_launch(void* const* d_in, const int* in_sizes, int n_in,
                              void* d_out, int out_size, void* d_ws, size_t ws_size,
                              hipStream_t stream) {
    const float* x     = (const float*)d_in[0];
    const int*   eidx  = (const int*)d_in[1];
    const int*   etype = (const int*)d_in[2];
    const float* rw    = (const float*)d_in[3];
    const float* sw    = (const float*)d_in[4];
    const float* bias  = (const float*)d_in[5];
    float* out = (float*)d_out;
    const int* src = eidx;
    const int* dst = eidx + N_EDGES;

    // ---- workspace layout ----
    int* counts_rel = (int*)d_ws;                  // 16
    int* cursor_rel = counts_rel + 16;             // 16
    int* seg        = cursor_rel + 16;             // 32 (17 used)
    int* part       = seg + 32;                    // 512
    int* dst_count  = part + 512;                  // N
    int* row_ptr    = dst_count + N_NODES;         // N+1
    int* cursor_dst = row_ptr + N_NODES + 1;       // N
    int* sorted     = cursor_dst + N_NODES;        // E+PAD
    int* pos        = sorted + N_EDGES + PAD;      // E+PAD
    size_t off = (((char*)(pos + N_EDGES + PAD) - (char*)d_ws) + 255) & ~(size_t)255;
    u16* xb   = (u16*)((char*)d_ws + off);         // N*128 bf16
    u16* wtb  = xb + (size_t)N_NODES * 128;        // 17*16384 bf16 (transposed)
    u16* msgs = wtb + 17 * 16384;                  // (E+PAD)*128 bf16, dst-grouped
    size_t need = (size_t)((char*)(msgs + (size_t)(N_EDGES + PAD) * 128) - (char*)d_ws);

    const int EB  = (N_EDGES + 255) / 256;         // 2500
    const int EBP = (N_EDGES + PAD) / 256;         // 2504

    if (ws_size >= need) {
        hipMemsetAsync(d_ws, 0, (size_t)(576 + N_NODES) * sizeof(int), stream);
        k_cvt_x<<<N_NODES * IN_DIM / 4 / 256, 256, 0, stream>>>(x, xb);
        k_cvt_w<<<17 * 16384 / 256, 256, 0, stream>>>(rw, sw, wtb);
        k_hist<<<EB, 256, 0, stream>>>(etype, dst, counts_rel, dst_count);
        k_scan_rel_pad<<<1, 64, 0, stream>>>(counts_rel, cursor_rel, seg);
        k_fill<<<1, 256, 0, stream>>>(counts_rel, seg, sorted);
        k_scatter_rel<<<EB, 256, 0, stream>>>(etype, cursor_rel, sorted);
        k_scan1<<<NB_SCAN, 256, 0, stream>>>(dst_count, row_ptr, part);
        k_scan2<<<1, 512, 0, stream>>>(part);
        k_scan3<<<NB_SCAN, 256, 0, stream>>>(row_ptr, part, cursor_dst);
        k_pos<<<EBP, 256, 0, stream>>>(sorted, dst, cursor_dst, pos);

        k_self_mfma<<<(N_NODES + 255) / 256, 256, 0, stream>>>(xb, wtb, bias, out);
        k_msg_mfma<<<EBP, 256, 0, stream>>>(xb, wtb, src, etype, sorted, pos, msgs);
        k_gather<<<(N_NODES * 64 + 255) / 256, 256, 0, stream>>>(row_ptr, msgs, out);
    } else {
        // fallback: atomic path (needs only rel-sort scratch)
        hipMemsetAsync(counts_rel, 0, 16 * sizeof(int), stream);
        k_hist_rel<<<EB, 256, 0, stream>>>(etype, counts_rel);
        k_scan_rel<<<1, 64, 0, stream>>>(counts_rel, cursor_rel);
        k_scatter_rel<<<EB, 256, 0, stream>>>(etype, cursor_rel, sorted);
        k_self_old<<<N_NODES / 8, 128, 0, stream>>>(x, sw, bias, out);
        k_edge_atomic<<<N_EDGES / EPB, 256, 0, stream>>>(x, rw, src, dst, etype, sorted, out);
        k_relu<<<(N_NODES * OUT_DIM / 4 + 255) / 256, 256, 0, stream>>>(out);
    }
}